// Round 1
// baseline (1551.403 us; speedup 1.0000x reference)
//
#include <hip/hip_runtime.h>

#define OBS    8268
#define NA     43
#define TSTEPS 128
#define BATCH  256
#define HID    32
#define ROWS   (TSTEPS*BATCH)     // 32768
#define KFULL  258                // full 32-wide K blocks
#define KBLK   259                // padded K blocks (8288 = 259*32)

typedef __attribute__((ext_vector_type(8))) short short8_t;   // 8 bf16 (4 VGPRs)
typedef __attribute__((ext_vector_type(4))) float f32x4_t;    // MFMA acc

__device__ __forceinline__ short f2bf(float f) {
  // round-to-nearest-even f32 -> bf16 bits
  union { float f; unsigned u; } c; c.f = f;
  unsigned u = c.u;
  return (short)((u + 0x7fffu + ((u >> 16) & 1u)) >> 16);
}
__device__ __forceinline__ float fast_sig(float x)  { return 1.f / (1.f + __expf(-x)); }
__device__ __forceinline__ float fast_tanh(float x) { float e = __expf(2.f * x); return 1.f - 2.f / (e + 1.f); }

// ---------------------------------------------------------------------------
// K1: W1 [64][8268] fp32 -> bf16 MFMA-B layout [kb][n=64][kk=32], /255 folded,
// zero-padded to K=8288.
// ---------------------------------------------------------------------------
__global__ __launch_bounds__(256) void k_prep(const float* __restrict__ W1,
                                              short* __restrict__ w1bf) {
  int idx = blockIdx.x * 256 + threadIdx.x;
  if (idx >= KBLK * 2048) return;
  int kb  = idx >> 11;
  int rem = idx & 2047;
  int n   = rem >> 5;
  int kk  = rem & 31;
  int k   = kb * 32 + kk;
  float v = 0.f;
  if (k < OBS) v = W1[n * OBS + k] * (1.f / 255.f);
  w1bf[idx] = f2bf(v);
}

// ---------------------------------------------------------------------------
// K2: per block: 64 rows of x. MFMA bf16 layer-1 (K=8268), then fused fp32
// layers 2/3 + Wih projection -> xg [32768][128].
// Wave w handles rows m0+w*16..+15; A-frag loaded straight from global
// (lane: row=m16, k=quad*8..+7), B-frag from w1bf (perfectly coalesced 1KB).
// ---------------------------------------------------------------------------
__global__ __launch_bounds__(256) void k_encoder(
    const float* __restrict__ x, const short* __restrict__ w1bf,
    const float* __restrict__ b1, const float* __restrict__ W2,
    const float* __restrict__ b2, const float* __restrict__ W3,
    const float* __restrict__ b3, const float* __restrict__ Wih,
    const float* __restrict__ bih, const float* __restrict__ bhh,
    float* __restrict__ xg) {
  __shared__ __align__(16) float hbuf[64][68];   // h1 / h2 / h3 (pad 68: 16B-aligned rows, odd word-stride banks)
  __shared__ __align__(16) float wbuf[4608];     // W2[64][68] / W3[32][68] / Wih[128][36]

  const int tid  = threadIdx.x;
  const int lane = tid & 63;
  const int wv   = tid >> 6;
  const int m16  = lane & 15;
  const int quad = lane >> 4;
  const int m0   = blockIdx.x * 64;
  const int arow = m0 + wv * 16 + m16;
  const float* __restrict__ xrow = x + (size_t)arow * OBS;
  const short8_t* __restrict__ bbase = (const short8_t*)w1bf;

  f32x4_t acc0 = {0,0,0,0}, acc1 = {0,0,0,0}, acc2 = {0,0,0,0}, acc3 = {0,0,0,0};

  // software pipeline: 1-deep prefetch of A (global, HBM) and B (L1/L2-hot)
  float4 A0, A1;
  short8_t B0, B1, B2, B3;
  {
    const float4* p = (const float4*)(xrow + quad * 8);
    A0 = p[0]; A1 = p[1];
    const short8_t* bp = bbase + quad;
    B0 = bp[(0  + m16) * 4];
    B1 = bp[(16 + m16) * 4];
    B2 = bp[(32 + m16) * 4];
    B3 = bp[(48 + m16) * 4];
  }
  for (int kb = 0; kb < KFULL; ++kb) {
    float4 a0 = A0, a1 = A1;
    short8_t b0 = B0, b1v = B1, b2v = B2, b3v = B3;
    if (kb + 1 < KFULL) {
      const float4* p = (const float4*)(xrow + (kb + 1) * 32 + quad * 8);
      A0 = p[0]; A1 = p[1];
      const short8_t* bp = bbase + (size_t)(kb + 1) * 256 + quad;
      B0 = bp[(0  + m16) * 4];
      B1 = bp[(16 + m16) * 4];
      B2 = bp[(32 + m16) * 4];
      B3 = bp[(48 + m16) * 4];
    }
    short8_t af;
    af[0] = f2bf(a0.x); af[1] = f2bf(a0.y); af[2] = f2bf(a0.z); af[3] = f2bf(a0.w);
    af[4] = f2bf(a1.x); af[5] = f2bf(a1.y); af[6] = f2bf(a1.z); af[7] = f2bf(a1.w);
    acc0 = __builtin_amdgcn_mfma_f32_16x16x32_bf16(af, b0,  acc0, 0, 0, 0);
    acc1 = __builtin_amdgcn_mfma_f32_16x16x32_bf16(af, b1v, acc1, 0, 0, 0);
    acc2 = __builtin_amdgcn_mfma_f32_16x16x32_bf16(af, b2v, acc2, 0, 0, 0);
    acc3 = __builtin_amdgcn_mfma_f32_16x16x32_bf16(af, b3v, acc3, 0, 0, 0);
  }
  { // remainder K block (12 valid k), B side already zero-padded
    const int kb = KFULL;
    float a[8];
#pragma unroll
    for (int j = 0; j < 8; ++j) {
      int k = kb * 32 + quad * 8 + j;
      a[j] = (k < OBS) ? xrow[k] : 0.f;
    }
    short8_t af;
#pragma unroll
    for (int j = 0; j < 8; ++j) af[j] = f2bf(a[j]);
    const short8_t* bp = bbase + (size_t)kb * 256 + quad;
    acc0 = __builtin_amdgcn_mfma_f32_16x16x32_bf16(af, bp[(0  + m16) * 4], acc0, 0, 0, 0);
    acc1 = __builtin_amdgcn_mfma_f32_16x16x32_bf16(af, bp[(16 + m16) * 4], acc1, 0, 0, 0);
    acc2 = __builtin_amdgcn_mfma_f32_16x16x32_bf16(af, bp[(32 + m16) * 4], acc2, 0, 0, 0);
    acc3 = __builtin_amdgcn_mfma_f32_16x16x32_bf16(af, bp[(48 + m16) * 4], acc3, 0, 0, 0);
  }

  // epilogue: h1 = tanh(acc + b1) -> hbuf   (C/D layout: col=lane&15, row=quad*4+reg)
#pragma unroll
  for (int r = 0; r < 4; ++r) {
    int row = wv * 16 + quad * 4 + r;
    hbuf[row][ 0 + m16] = fast_tanh(acc0[r] + b1[ 0 + m16]);
    hbuf[row][16 + m16] = fast_tanh(acc1[r] + b1[16 + m16]);
    hbuf[row][32 + m16] = fast_tanh(acc2[r] + b1[32 + m16]);
    hbuf[row][48 + m16] = fast_tanh(acc3[r] + b1[48 + m16]);
  }
  { // stage W2 [64][64] -> wbuf stride 68
    int r  = tid >> 2;
    int c0 = (tid & 3) * 16;
    const float4* src = (const float4*)(W2 + r * 64 + c0);
    float4* dst = (float4*)(&wbuf[r * 68 + c0]);
    dst[0] = src[0]; dst[1] = src[1]; dst[2] = src[2]; dst[3] = src[3];
  }
  __syncthreads();

  // layer 2: h2 = tanh(h1 @ W2^T + b2). thread: row r=tid&63, cols (tid>>6)*16..+15
  float o2[16];
  {
    const int r  = tid & 63;
    const int c0 = (tid >> 6) * 16;
#pragma unroll
    for (int i = 0; i < 16; ++i) o2[i] = 0.f;
    for (int k = 0; k < 64; k += 4) {
      float4 h4 = *(const float4*)(&hbuf[r][k]);
#pragma unroll
      for (int i = 0; i < 16; ++i) {
        float4 w4 = *(const float4*)(&wbuf[(c0 + i) * 68 + k]);  // wave-uniform -> LDS broadcast
        o2[i] += h4.x * w4.x + h4.y * w4.y + h4.z * w4.z + h4.w * w4.w;
      }
    }
  }
  __syncthreads();
  {
    const int r  = tid & 63;
    const int c0 = (tid >> 6) * 16;
#pragma unroll
    for (int i = 0; i < 16; ++i) hbuf[r][c0 + i] = fast_tanh(o2[i] + b2[c0 + i]);
  }
  if (tid < 128) { // stage W3 [32][64] -> wbuf stride 68
    int r  = tid >> 2;
    int c0 = (tid & 3) * 16;
    const float4* src = (const float4*)(W3 + r * 64 + c0);
    float4* dst = (float4*)(&wbuf[r * 68 + c0]);
    dst[0] = src[0]; dst[1] = src[1]; dst[2] = src[2]; dst[3] = src[3];
  }
  __syncthreads();

  // layer 3: h3 = tanh(h2 @ W3^T + b3). thread: row r, cols (tid>>6)*8..+7
  float o3[8];
  {
    const int r  = tid & 63;
    const int c0 = (tid >> 6) * 8;
#pragma unroll
    for (int i = 0; i < 8; ++i) o3[i] = 0.f;
    for (int k = 0; k < 64; k += 4) {
      float4 h4 = *(const float4*)(&hbuf[r][k]);
#pragma unroll
      for (int i = 0; i < 8; ++i) {
        float4 w4 = *(const float4*)(&wbuf[(c0 + i) * 68 + k]);
        o3[i] += h4.x * w4.x + h4.y * w4.y + h4.z * w4.z + h4.w * w4.w;
      }
    }
  }
  __syncthreads();
  {
    const int r  = tid & 63;
    const int c0 = (tid >> 6) * 8;
#pragma unroll
    for (int i = 0; i < 8; ++i) hbuf[r][c0 + i] = fast_tanh(o3[i] + b3[c0 + i]);
  }
  { // stage Wih [128][32] -> wbuf stride 36
    int g  = tid >> 1;
    int k0 = (tid & 1) * 16;
    const float4* src = (const float4*)(Wih + g * 32 + k0);
    float4* dst = (float4*)(&wbuf[g * 36 + k0]);
    dst[0] = src[0]; dst[1] = src[1]; dst[2] = src[2]; dst[3] = src[3];
  }
  __syncthreads();

  // layer 4: xg = h3 @ Wih^T + (bih+bhh). thread: row r, gates (tid>>6)*32..+31
  {
    const int r  = tid & 63;
    const int g0 = (tid >> 6) * 32;
    float o4[32];
#pragma unroll
    for (int i = 0; i < 32; ++i) o4[i] = 0.f;
    for (int k = 0; k < 32; k += 4) {
      float4 h4 = *(const float4*)(&hbuf[r][k]);
#pragma unroll
      for (int i = 0; i < 32; ++i) {
        float4 w4 = *(const float4*)(&wbuf[(g0 + i) * 36 + k]);
        o4[i] += h4.x * w4.x + h4.y * w4.y + h4.z * w4.z + h4.w * w4.w;
      }
    }
    float* dst = xg + (size_t)(m0 + r) * 128 + g0;
#pragma unroll
    for (int i = 0; i < 32; i += 4) {
      float4 v;
      v.x = o4[i + 0] + bih[g0 + i + 0] + bhh[g0 + i + 0];
      v.y = o4[i + 1] + bih[g0 + i + 1] + bhh[g0 + i + 1];
      v.z = o4[i + 2] + bih[g0 + i + 2] + bhh[g0 + i + 2];
      v.w = o4[i + 3] + bih[g0 + i + 3] + bhh[g0 + i + 3];
      *(float4*)(dst + i) = v;
    }
  }
}

// ---------------------------------------------------------------------------
// K3: LSTM scan + fused heads. One wave per batch element (recurrence is
// independent per element). Lane l owns gates l and 64+l:
//   l<32: (i_l, g_l);  l>=32: (f_{l-32}, o_{l-32}) -> shfl_xor(32) pairs them.
// Whh rows in VGPRs; hs broadcast via 128B LDS; t+1 inputs prefetched.
// ---------------------------------------------------------------------------
__global__ __launch_bounds__(64) void k_lstm(
    const float* __restrict__ xg, const float* __restrict__ done,
    const float* __restrict__ h0, const float* __restrict__ c0,
    const float* __restrict__ Whh, const float* __restrict__ Wa,
    const float* __restrict__ ba, const float* __restrict__ Wc,
    const float* __restrict__ bc, float* __restrict__ out) {
  const int b = blockIdx.x;
  const int l = threadIdx.x;
  __shared__ __align__(16) float lhs[HID];

  float w0[HID], w1[HID];
#pragma unroll
  for (int k = 0; k < HID; k += 4) {
    *(float4*)&w0[k] = *(const float4*)(Whh + l * HID + k);
    *(float4*)&w1[k] = *(const float4*)(Whh + (64 + l) * HID + k);
  }
  float wa[HID];
  float hb = 0.f;
  if (l < NA) {
#pragma unroll
    for (int k = 0; k < HID; k += 4) *(float4*)&wa[k] = *(const float4*)(Wa + l * HID + k);
    hb = ba[l];
  } else if (l == NA) {
#pragma unroll
    for (int k = 0; k < HID; k += 4) *(float4*)&wa[k] = *(const float4*)(Wc + k);
    hb = bc[0];
  } else {
#pragma unroll
    for (int k = 0; k < HID; ++k) wa[k] = 0.f;
  }

  float hs = 0.f, cs = 0.f;
  if (l < HID) { hs = h0[b * HID + l]; cs = c0[b * HID + l]; }

  // prefetch t=0 inputs
  float pg0 = xg[(size_t)b * 128 + l];
  float pg1 = xg[(size_t)b * 128 + 64 + l];
  float pd  = done[b];

  for (int t = 0; t < TSTEPS; ++t) {
    const int tb = t * BATCH + b;
    float g0 = pg0, g1 = pg1;
    const float m = 1.f - pd;
    if (t + 1 < TSTEPS) { // prefetch next step (hides ~900cyc HBM/L2 latency)
      const float* nx = xg + (size_t)(tb + BATCH) * 128;
      pg0 = nx[l];
      pg1 = nx[64 + l];
      pd  = done[tb + BATCH];
    }
    if (l < HID) {
      hs *= m; cs *= m;
      lhs[l] = hs;
    }
    __syncthreads();
    float h[HID];
#pragma unroll
    for (int k = 0; k < HID; k += 4) *(float4*)&h[k] = *(const float4*)&lhs[k];
#pragma unroll
    for (int k = 0; k < HID; ++k) {
      g0 = fmaf(w0[k], h[k], g0);
      g1 = fmaf(w1[k], h[k], g1);
    }
    float fg = __shfl_xor(g0, 32, 64);
    float og = __shfl_xor(g1, 32, 64);
    __syncthreads();
    if (l < HID) {
      float ig = fast_sig(g0);
      float gg = fast_tanh(g1);
      float ff = fast_sig(fg);
      float oo = fast_sig(og);
      cs = ff * cs + ig * gg;
      hs = oo * fast_tanh(cs);
      lhs[l] = hs;
    }
    __syncthreads();
#pragma unroll
    for (int k = 0; k < HID; k += 4) *(float4*)&h[k] = *(const float4*)&lhs[k];
    if (l <= NA) { // fused heads: lanes 0..42 logits, lane 43 value
      float a = hb;
#pragma unroll
      for (int k = 0; k < HID; ++k) a = fmaf(wa[k], h[k], a);
      out[(size_t)tb * (NA + 1) + l] = a;
    }
  }
  if (l < HID) {
    out[(size_t)ROWS * (NA + 1) + b * HID + l] = hs;
    out[(size_t)ROWS * (NA + 1) + BATCH * HID + b * HID + l] = cs;
  }
}

// ---------------------------------------------------------------------------
extern "C" void kernel_launch(void* const* d_in, const int* in_sizes, int n_in,
                              void* d_out, int out_size, void* d_ws, size_t ws_size,
                              hipStream_t stream) {
  const float* x    = (const float*)d_in[0];
  const float* done = (const float*)d_in[1];
  const float* h0   = (const float*)d_in[2];
  const float* c0   = (const float*)d_in[3];
  const float* W1   = (const float*)d_in[4];
  const float* b1   = (const float*)d_in[5];
  const float* W2   = (const float*)d_in[6];
  const float* b2   = (const float*)d_in[7];
  const float* W3   = (const float*)d_in[8];
  const float* b3   = (const float*)d_in[9];
  const float* Wih  = (const float*)d_in[10];
  const float* Whh  = (const float*)d_in[11];
  const float* bih  = (const float*)d_in[12];
  const float* bhh  = (const float*)d_in[13];
  const float* Wa   = (const float*)d_in[14];
  const float* ba   = (const float*)d_in[15];
  const float* Wc   = (const float*)d_in[16];
  const float* bc   = (const float*)d_in[17];
  float* out = (float*)d_out;

  // workspace: xg [32768*128] f32 (16.78 MB) | w1bf [259*2048] bf16 (1.06 MB)
  float* xg   = (float*)d_ws;
  short* w1bf = (short*)((char*)d_ws + (size_t)ROWS * 128 * sizeof(float));

  k_prep<<<(KBLK * 2048) / 256, 256, 0, stream>>>(W1, w1bf);
  k_encoder<<<ROWS / 64, 256, 0, stream>>>(x, w1bf, b1, W2, b2, W3, b3,
                                           Wih, bih, bhh, xg);
  k_lstm<<<BATCH, 64, 0, stream>>>(xg, done, h0, c0, Whh, Wa, ba, Wc, bc, out);
}